// Round 11
// baseline (819.559 us; speedup 1.0000x reference)
//
#include <hip/hip_runtime.h>
#include <stdint.h>

// VQ: B=131072 rows, K=4096 codes, D=64, fp32 in/out.
// out = [B*D floats quantized_st][1 float loss]
//
// bf16 split-precision MFMA distance search (3-product exact-split), top-2
// tracking with the CHUNK INDEX PACKED into the score's low mantissa byte,
// fp64 rescan of rows whose packed score gap < TAU. K-SPLIT (r9 geometry:
// 64 rows/wave, waves 2t/2t+1 share rows scan disjoint K halves, 1024 blocks).
// NEW vs r9: the -0.5|c|^2 bias rides a 5th B-block (k-slots 0,1 = bf16 hi/lo
// of the norm) and enters via ONE norm-MFMA whose output is the shared C input
// of all 4 row-tile chains -> kills 16 acc-init v_movs + the sneg LDS array +
// its staging loop/barrier (r9 was issue-bound: VALU 53% + MFMA 46% = 99%).
constexpr int Bn = 131072, Kn = 4096, Dn = 64;
constexpr int NCHUNK = 256;          // K / 16 codes per chunk (c fits in 8 bits)
constexpr int HCHUNK = 128;          // chunks per K-half
constexpr int CBYTES = 5120;         // 4x1KB (B0..B3) + 1KB norm block (B4)
constexpr float TAU_S = 0.02f;       // covers split ~1e-3 + pack ~4e-3 + norm ~1e-3

typedef short bf16x8 __attribute__((ext_vector_type(8)));
typedef float f32x4  __attribute__((ext_vector_type(4)));

__device__ __forceinline__ uint32_t rneb(float f) {           // bf16 RNE bits
    uint32_t u = __float_as_uint(f);
    return (u + 0x7FFFu + ((u >> 16) & 1u)) >> 16;
}
__device__ __forceinline__ float bfval(uint32_t b) { return __uint_as_float(b << 16); }

struct Split8 { bf16x8 hi, lo; };
__device__ __forceinline__ Split8 split8(float4 a, float4 b) {
    uint32_t h0=rneb(a.x),h1=rneb(a.y),h2=rneb(a.z),h3=rneb(a.w);
    uint32_t h4=rneb(b.x),h5=rneb(b.y),h6=rneb(b.z),h7=rneb(b.w);
    uint32_t l0=rneb(a.x-bfval(h0)), l1=rneb(a.y-bfval(h1));
    uint32_t l2=rneb(a.z-bfval(h2)), l3=rneb(a.w-bfval(h3));
    uint32_t l4=rneb(b.x-bfval(h4)), l5=rneb(b.y-bfval(h5));
    uint32_t l6=rneb(b.z-bfval(h6)), l7=rneb(b.w-bfval(h7));
    union { bf16x8 v; uint32_t u[4]; } H, L;
    H.u[0]=h0|(h1<<16); H.u[1]=h2|(h3<<16); H.u[2]=h4|(h5<<16); H.u[3]=h6|(h7<<16);
    L.u[0]=l0|(l1<<16); L.u[1]=l2|(l3<<16); L.u[2]=l4|(l5<<16); L.u[3]=l6|(l7<<16);
    Split8 r; r.hi = H.v; r.lo = L.v; return r;
}

// ---- prep: codebook -> fragment-major split-bf16 image (5KB per 16-code chunk) ----
// chunk: [B0][B1] = hi feats 0..31/32..63, [B2][B3] = lo, [B4] = norm block:
// lane j (g=0) holds (nh, nl, 0...) = bf16 hi/lo of -0.5|c_j|^2 at k-slots 0,1.
__global__ __launch_bounds__(256) void vq_prep(const float* __restrict__ cb,
                                               uint8_t* __restrict__ stage) {
    int t = blockIdx.x * 256 + threadIdx.x;     // 0..32767, one per 8 floats
    int code = t >> 3, oct = t & 7;
    const float4* cp = (const float4*)(cb + (size_t)code * Dn + oct * 8);
    float4 f0 = cp[0], f1 = cp[1];
    Split8 s = split8(f0, f1);
    int j = code & 15, cc = code >> 4;
    uint8_t* base = stage + (size_t)cc * CBYTES;
    int dsto = (((oct & 3) * 16 + j) << 4) + ((oct & 4) ? 1024 : 0);
    *(bf16x8*)(base + dsto)        = s.hi;
    *(bf16x8*)(base + 2048 + dsto) = s.lo;
    float n = f0.x*f0.x + f0.y*f0.y + f0.z*f0.z + f0.w*f0.w
            + f1.x*f1.x + f1.y*f1.y + f1.z*f1.z + f1.w*f1.w;
    n += __shfl_xor(n, 1); n += __shfl_xor(n, 2); n += __shfl_xor(n, 4);
    if (oct == 0) {
        float nn = -0.5f * n;
        uint32_t nh = rneb(nn);
        uint32_t nl = rneb(nn - bfval(nh));
        uint4 z = { nh | (nl << 16), 0u, 0u, 0u };
        *(uint4*)(base + 4096 + j * 16) = z;            // g=0 lane data
    } else if (oct <= 3) {
        uint4 z = { 0u, 0u, 0u, 0u };
        *(uint4*)(base + 4096 + oct * 256 + j * 16) = z; // g=1..3 zeros
    }
}

__global__ void vq_zero(float* __restrict__ loss_acc, int* __restrict__ flag_cnt) {
    *loss_acc = 0.0f; *flag_cnt = 0;
}

// 1024 blocks x 256 thr; 4 waves: (row-tile = w>>1) x (K-half = w&1); 64 rows/wave.
__global__ __launch_bounds__(256, 3) void vq_main(
    const float* __restrict__ x, const uint8_t* __restrict__ stage,
    const float* __restrict__ cb, float* __restrict__ out,
    float* __restrict__ loss_acc, int* __restrict__ flag_cnt,
    int* __restrict__ flag_rows) {

    __shared__ float smv1[4][64], smv2[4][64];
    __shared__ int   smk[4][64];
    __shared__ int   sres[128];

    const int tid = threadIdx.x;
    const int lane = tid & 63, w = tid >> 6;
    const int g = lane >> 4, j = lane & 15;
    const int kh = w & 1;                // K-half
    const int cstart = kh * HCHUNK;

    // A fragments: 4 sub-tiles of 16 rows (A layout: row=lane&15, k=(lane>>4)*8+e)
    const int rowbase = blockIdx.x * 128 + (w >> 1) * 64;
    bf16x8 ah[4][2], al[4][2];
    #pragma unroll
    for (int t = 0; t < 4; ++t) {
        const float* xr = x + (size_t)(rowbase + t*16 + j) * Dn + g*8;
        Split8 s0 = split8(*(const float4*)xr,        *(const float4*)(xr + 4));
        Split8 s1 = split8(*(const float4*)(xr + 32), *(const float4*)(xr + 36));
        ah[t][0] = s0.hi; al[t][0] = s0.lo;
        ah[t][1] = s1.hi; al[t][1] = s1.lo;
    }

    // constant A-frag (1,1,0,...) for the norm-MFMA, and a zero C tuple
    bf16x8 acst;
    {
        union { bf16x8 v; uint32_t u[4]; } A;
        A.u[0] = (lane < 16) ? 0x3F803F80u : 0u;   // k=0,1 -> bf16 1.0
        A.u[1] = 0u; A.u[2] = 0u; A.u[3] = 0u;
        acst = A.v;
    }
    const f32x4 zero4 = {0.f, 0.f, 0.f, 0.f};

    // packed top-2: score low byte carries the chunk index (b1 >= b2 invariant)
    float b1[16], b2[16];
    #pragma unroll
    for (int s = 0; s < 16; ++s) { b1[s] = -3.4e38f; b2[s] = -3.4e38f; }

    // 2-deep register prefetch of B fragments straight from L2 (no LDS, no barriers)
    const uint8_t* sp = stage + (lane << 4);
    bf16x8 Bf[2][5];
    #pragma unroll
    for (int p = 0; p < 2; ++p) {
        const uint8_t* bbp = sp + (size_t)(cstart + p) * CBYTES;
        Bf[p][0] = *(const bf16x8*)(bbp);
        Bf[p][1] = *(const bf16x8*)(bbp + 1024);
        Bf[p][2] = *(const bf16x8*)(bbp + 2048);
        Bf[p][3] = *(const bf16x8*)(bbp + 3072);
        Bf[p][4] = *(const bf16x8*)(bbp + 4096);
    }

#define TOP2(ACC, BASE)                                                       \
    _Pragma("unroll")                                                         \
    for (int q = 0; q < 4; ++q) {                                             \
        int s = (BASE) + q;                                                   \
        uint32_t vb = (__float_as_uint(ACC[q]) & 0xFFFFFF00u) | c_;           \
        float vp = __uint_as_float(vb);                                       \
        float ob1 = b1[s];                                                    \
        b2[s] = __builtin_amdgcn_fmed3f(vp, ob1, b2[s]);                      \
        b1[s] = fmaxf(ob1, vp);                                               \
    }

#define CHUNK_BODY(P, C, RELOAD)                                              \
    {                                                                         \
        const uint32_t c_ = (uint32_t)(C);                                    \
        bf16x8 B0 = Bf[P][0], B1 = Bf[P][1], B2 = Bf[P][2], B3 = Bf[P][3];    \
        bf16x8 B4 = Bf[P][4];                                                 \
        /* norm-MFMA: every row of nacc = nh[col]+nl[col] = -0.5|c_col|^2 */  \
        f32x4 nacc = __builtin_amdgcn_mfma_f32_16x16x32_bf16(acst, B4, zero4, 0,0,0); \
        f32x4 a0 = __builtin_amdgcn_mfma_f32_16x16x32_bf16(ah[0][0], B0, nacc, 0,0,0);\
        f32x4 a1 = __builtin_amdgcn_mfma_f32_16x16x32_bf16(ah[1][0], B0, nacc, 0,0,0);\
        f32x4 a2 = __builtin_amdgcn_mfma_f32_16x16x32_bf16(ah[2][0], B0, nacc, 0,0,0);\
        f32x4 a3 = __builtin_amdgcn_mfma_f32_16x16x32_bf16(ah[3][0], B0, nacc, 0,0,0);\
        a0 = __builtin_amdgcn_mfma_f32_16x16x32_bf16(ah[0][1], B1, a0, 0,0,0);\
        a1 = __builtin_amdgcn_mfma_f32_16x16x32_bf16(ah[1][1], B1, a1, 0,0,0);\
        a2 = __builtin_amdgcn_mfma_f32_16x16x32_bf16(ah[2][1], B1, a2, 0,0,0);\
        a3 = __builtin_amdgcn_mfma_f32_16x16x32_bf16(ah[3][1], B1, a3, 0,0,0);\
        a0 = __builtin_amdgcn_mfma_f32_16x16x32_bf16(al[0][0], B0, a0, 0,0,0);\
        a1 = __builtin_amdgcn_mfma_f32_16x16x32_bf16(al[1][0], B0, a1, 0,0,0);\
        a2 = __builtin_amdgcn_mfma_f32_16x16x32_bf16(al[2][0], B0, a2, 0,0,0);\
        a3 = __builtin_amdgcn_mfma_f32_16x16x32_bf16(al[3][0], B0, a3, 0,0,0);\
        a0 = __builtin_amdgcn_mfma_f32_16x16x32_bf16(al[0][1], B1, a0, 0,0,0);\
        a1 = __builtin_amdgcn_mfma_f32_16x16x32_bf16(al[1][1], B1, a1, 0,0,0);\
        a2 = __builtin_amdgcn_mfma_f32_16x16x32_bf16(al[2][1], B1, a2, 0,0,0);\
        a3 = __builtin_amdgcn_mfma_f32_16x16x32_bf16(al[3][1], B1, a3, 0,0,0);\
        a0 = __builtin_amdgcn_mfma_f32_16x16x32_bf16(ah[0][0], B2, a0, 0,0,0);\
        a1 = __builtin_amdgcn_mfma_f32_16x16x32_bf16(ah[1][0], B2, a1, 0,0,0);\
        a2 = __builtin_amdgcn_mfma_f32_16x16x32_bf16(ah[2][0], B2, a2, 0,0,0);\
        a3 = __builtin_amdgcn_mfma_f32_16x16x32_bf16(ah[3][0], B2, a3, 0,0,0);\
        a0 = __builtin_amdgcn_mfma_f32_16x16x32_bf16(ah[0][1], B3, a0, 0,0,0);\
        a1 = __builtin_amdgcn_mfma_f32_16x16x32_bf16(ah[1][1], B3, a1, 0,0,0);\
        a2 = __builtin_amdgcn_mfma_f32_16x16x32_bf16(ah[2][1], B3, a2, 0,0,0);\
        a3 = __builtin_amdgcn_mfma_f32_16x16x32_bf16(ah[3][1], B3, a3, 0,0,0);\
        if (RELOAD) {   /* prefetch chunk c_+2 into this slot */              \
            const uint8_t* nb = sp + (size_t)(c_ + 2) * CBYTES;               \
            Bf[P][0] = *(const bf16x8*)(nb);                                  \
            Bf[P][1] = *(const bf16x8*)(nb + 1024);                           \
            Bf[P][2] = *(const bf16x8*)(nb + 2048);                           \
            Bf[P][3] = *(const bf16x8*)(nb + 3072);                           \
            Bf[P][4] = *(const bf16x8*)(nb + 4096);                           \
        }                                                                     \
        TOP2(a0, 0) TOP2(a1, 4) TOP2(a2, 8) TOP2(a3, 12)                      \
    }

    #pragma unroll 1
    for (int c4 = cstart; c4 < cstart + HCHUNK - 2; c4 += 2) {
        CHUNK_BODY(0, c4 + 0, true)
        CHUNK_BODY(1, c4 + 1, true)
    }
    CHUNK_BODY(0, cstart + HCHUNK - 2, false)
    CHUNK_BODY(1, cstart + HCHUNK - 1, false)
#undef CHUNK_BODY
#undef TOP2

    // per-row merge across the 16 code-lanes (D layout: row=(lane>>4)*4+q, col=lane&15)
    #pragma unroll
    for (int s = 0; s < 16; ++s) {
        float v1 = b1[s], v2 = b2[s];
        int kk = (int)((__float_as_uint(v1) & 0xFFu) << 4) + j;   // c*16 + j
        #pragma unroll
        for (int m = 1; m < 16; m <<= 1) {
            float p1 = __shfl_xor(v1, m);
            float p2 = __shfl_xor(v2, m);
            int pk = __shfl_xor(kk, m);
            v2 = fmaxf(fmaxf(v2, p2), fminf(v1, p1));
            bool take = (p1 > v1) || ((p1 == v1) && (pk < kk));
            v1 = take ? p1 : v1;
            kk = take ? pk : kk;
        }
        if (j == 0) {
            int row = (s >> 2)*16 + g*4 + (s & 3);   // 0..63 within wave
            smv1[w][row] = v1; smv2[w][row] = v2; smk[w][row] = kk;
        }
    }
    __syncthreads();

    // cross-K-half merge (disjoint k-ranges; near-ties all fall under TAU -> cleanup)
    if (tid < 128) {
        int rt = tid >> 6, r = tid & 63;
        int wa = rt * 2, wb = wa + 1;
        float v1a = smv1[wa][r], v2a = smv2[wa][r];
        float v1b = smv1[wb][r], v2b = smv2[wb][r];
        int   ka  = smk[wa][r],  kb  = smk[wb][r];
        bool take = v1b > v1a;
        float m1 = take ? v1b : v1a;
        int   kk = take ? kb  : ka;
        float m2 = fmaxf(fmaxf(v2a, v2b), fminf(v1a, v1b));
        int flag = ((m1 - m2) < TAU_S) ? (int)0x80000000 : 0;
        sres[tid] = kk | flag;
    }
    __syncthreads();

    // epilogue: fully coalesced; f enumerates (row, float4) pairs; 128 rows/block
    float ls = 0.f;
    const size_t blockrow = (size_t)blockIdx.x * 128;
    #pragma unroll 1
    for (int it = 0; it < 8; ++it) {
        int f = it * 256 + tid;
        int r = f >> 4, q = f & 15;
        int pk = sres[r];
        int idx = pk & 0x7FFFFFFF;
        bool flagged = pk < 0;
        size_t grow = blockrow + r;
        float4 xx = ((const float4*)(x + grow * Dn))[q];
        float4 qq = ((const float4*)(cb + (size_t)idx * Dn))[q];
        float dx = qq.x - xx.x, dy = qq.y - xx.y, dz = qq.z - xx.z, dw = qq.w - xx.w;
        float4 o; o.x = xx.x + dx; o.y = xx.y + dy; o.z = xx.z + dz; o.w = xx.w + dw;
        ((float4*)(out + grow * Dn))[q] = o;
        if (flagged) {
            if (q == 0) { int p = atomicAdd(flag_cnt, 1); flag_rows[p] = (int)grow; }
        } else {
            ls = fmaf(dx, dx, ls); ls = fmaf(dy, dy, ls);
            ls = fmaf(dz, dz, ls); ls = fmaf(dw, dw, ls);
        }
    }
    #pragma unroll
    for (int m = 1; m < 64; m <<= 1) ls += __shfl_xor(ls, m);
    if (lane == 0) atomicAdd(loss_acc, ls);
}

// fp64 full rescan of flagged rows, 8 rows per block-iteration (codebook read shared).
__global__ __launch_bounds__(256) void vq_cleanup(
    const float* __restrict__ x, const float* __restrict__ cb,
    const int* __restrict__ flag_cnt, const int* __restrict__ flag_rows,
    float* __restrict__ out, float* __restrict__ loss_acc) {
    __shared__ double sxd[8][Dn];
    __shared__ double swb[8][4];
    __shared__ int    swi[8][4];
    const int tid = threadIdx.x;
    const int n = *flag_cnt;

    for (int it = blockIdx.x; it * 8 < n; it += gridDim.x) {
        const int base = it * 8;
        const int nr = min(8, n - base);
        __syncthreads();   // protect sxd/swb from previous iteration readers
        {
            int rr = tid >> 5, e = tid & 31;
            int row = flag_rows[base + ((rr < nr) ? rr : 0)];
            sxd[rr][e]      = (double)x[(size_t)row * Dn + e];
            sxd[rr][e + 32] = (double)x[(size_t)row * Dn + e + 32];
        }
        __syncthreads();

        double best[8]; int bidx[8];
        #pragma unroll
        for (int r2 = 0; r2 < 8; ++r2) { best[r2] = 1.0e300; bidx[r2] = 0x7FFFFFFF; }

        #pragma unroll 1
        for (int i = 0; i < Kn / 256; ++i) {          // 16 codes per thread
            const int k = i * 256 + tid;
            const float* c4 = cb + (size_t)k * Dn;
            double cn = 0.0;
            double d0=0.0,d1=0.0,d2=0.0,d3=0.0,d4=0.0,d5=0.0,d6=0.0,d7=0.0;
            #pragma unroll 8
            for (int e = 0; e < Dn; ++e) {
                double ce = (double)c4[e];
                cn = fma(ce, ce, cn);
                d0 = fma(ce, sxd[0][e], d0);
                d1 = fma(ce, sxd[1][e], d1);
                d2 = fma(ce, sxd[2][e], d2);
                d3 = fma(ce, sxd[3][e], d3);
                d4 = fma(ce, sxd[4][e], d4);
                d5 = fma(ce, sxd[5][e], d5);
                d6 = fma(ce, sxd[6][e], d6);
                d7 = fma(ce, sxd[7][e], d7);
            }
            double dd[8] = { cn - 2.0*d0, cn - 2.0*d1, cn - 2.0*d2, cn - 2.0*d3,
                             cn - 2.0*d4, cn - 2.0*d5, cn - 2.0*d6, cn - 2.0*d7 };
            #pragma unroll
            for (int r2 = 0; r2 < 8; ++r2)
                if (dd[r2] < best[r2] || (dd[r2] == best[r2] && k < bidx[r2])) {
                    best[r2] = dd[r2]; bidx[r2] = k;
                }
        }
        // wave argmin then cross-wave merge (first-occurrence ties)
        #pragma unroll
        for (int r2 = 0; r2 < 8; ++r2) {
            double bb = best[r2]; int bi = bidx[r2];
            #pragma unroll
            for (int m = 1; m < 64; m <<= 1) {
                double pb = __shfl_xor(bb, m);
                int    pi = __shfl_xor(bi, m);
                if (pb < bb || (pb == bb && pi < bi)) { bb = pb; bi = pi; }
            }
            if ((tid & 63) == 0) { swb[r2][tid >> 6] = bb; swi[r2][tid >> 6] = bi; }
        }
        __syncthreads();
        if (tid < 8) {
            double fb = swb[tid][0]; int fi = swi[tid][0];
            #pragma unroll
            for (int wv = 1; wv < 4; ++wv) {
                double pb = swb[tid][wv]; int pi = swi[tid][wv];
                if (pb < fb || (pb == fb && pi < fi)) { fb = pb; fi = pi; }
            }
            swi[tid][0] = fi;
        }
        __syncthreads();

        if (tid < 128) {
            int r2 = tid >> 4, q = tid & 15;
            if (r2 < nr) {
                int row = flag_rows[base + r2];
                int fi  = swi[r2][0];
                float4 xx = ((const float4*)(x + (size_t)row * Dn))[q];
                float4 qq = ((const float4*)(cb + (size_t)fi * Dn))[q];
                float dx = qq.x - xx.x, dy = qq.y - xx.y, dz = qq.z - xx.z, dw = qq.w - xx.w;
                float4 o; o.x = xx.x + dx; o.y = xx.y + dy; o.z = xx.z + dz; o.w = xx.w + dw;
                ((float4*)(out + (size_t)row * Dn))[q] = o;
                float ls = dx*dx + dy*dy + dz*dz + dw*dw;
                ls += __shfl_xor(ls, 1); ls += __shfl_xor(ls, 2);
                ls += __shfl_xor(ls, 4); ls += __shfl_xor(ls, 8);
                if (q == 0) atomicAdd(loss_acc, ls);
            }
        }
    }
}

__global__ void vq_final(float* __restrict__ loss_acc) {
    *loss_acc = *loss_acc * (1.25f / (float)(Bn * Dn));
}

extern "C" void kernel_launch(void* const* d_in, const int* in_sizes, int n_in,
                              void* d_out, int out_size, void* d_ws, size_t ws_size,
                              hipStream_t stream) {
    const float* x  = (const float*)d_in[0];
    const float* cb = (const float*)d_in[1];
    float* out  = (float*)d_out;
    float* loss = out + (size_t)Bn * Dn;

    // ws layout: [stage 1.25MB][flag_cnt 4B][flag_rows 512KB]
    uint8_t* wsb = (uint8_t*)d_ws;
    uint8_t* stage     = wsb;
    int*     flag_cnt  = (int*)(wsb + (size_t)NCHUNK * CBYTES);
    int*     flag_rows = flag_cnt + 1;

    vq_prep<<<128, 256, 0, stream>>>(cb, stage);
    vq_zero<<<1, 1, 0, stream>>>(loss, flag_cnt);
    vq_main<<<Bn / 128, 256, 0, stream>>>(x, stage, cb, out, loss, flag_cnt, flag_rows);
    vq_cleanup<<<512, 256, 0, stream>>>(x, cb, flag_cnt, flag_rows, out, loss);
    vq_final<<<1, 1, 0, stream>>>(loss);
}

// Round 12
// 332.263 us; speedup vs baseline: 2.4666x; 2.4666x over previous
//
#include <hip/hip_runtime.h>
#include <stdint.h>

// VQ: B=131072 rows, K=4096 codes, D=64, fp32 in/out.
// out = [B*D floats quantized_st][1 float loss]
//
// bf16 split-precision MFMA distance search (3-product exact-split), top-2
// tracking with the CHUNK INDEX PACKED into the score's low mantissa byte
// (v_perm splice), fp64 rescan of rows whose packed score gap < TAU.
// K-SPLIT r9 geometry: 64 rows/wave, waves 2t/2t+1 share rows scan disjoint
// K halves, 1024 blocks. NEW vs r9: two-phase 8-reg B staging (ch -> 16 MFMA,
// reuse regs for cl -> 8 MFMA) shrinks live set to ~128 VGPR so
// launch_bounds(256,4) gives 4 waves/SIMD (r9 sat at 2 waves/SIMD in the
// (128,256] occupancy bucket -> latency-bound at 2.2x the matrix floor).
constexpr int Bn = 131072, Kn = 4096, Dn = 64;
constexpr int NCHUNK = 256;          // K / 16 codes per chunk (c fits in 8 bits)
constexpr int HCHUNK = 128;          // chunks per K-half
constexpr float TAU_S = 0.015f;      // covers split ~1e-3 + pack ~4e-3 per score

typedef short bf16x8 __attribute__((ext_vector_type(8)));
typedef float f32x4  __attribute__((ext_vector_type(4)));

__device__ __forceinline__ uint32_t rneb(float f) {           // bf16 RNE bits
    uint32_t u = __float_as_uint(f);
    return (u + 0x7FFFu + ((u >> 16) & 1u)) >> 16;
}
__device__ __forceinline__ float bfval(uint32_t b) { return __uint_as_float(b << 16); }

struct Split8 { bf16x8 hi, lo; };
__device__ __forceinline__ Split8 split8(float4 a, float4 b) {
    uint32_t h0=rneb(a.x),h1=rneb(a.y),h2=rneb(a.z),h3=rneb(a.w);
    uint32_t h4=rneb(b.x),h5=rneb(b.y),h6=rneb(b.z),h7=rneb(b.w);
    uint32_t l0=rneb(a.x-bfval(h0)), l1=rneb(a.y-bfval(h1));
    uint32_t l2=rneb(a.z-bfval(h2)), l3=rneb(a.w-bfval(h3));
    uint32_t l4=rneb(b.x-bfval(h4)), l5=rneb(b.y-bfval(h5));
    uint32_t l6=rneb(b.z-bfval(h6)), l7=rneb(b.w-bfval(h7));
    union { bf16x8 v; uint32_t u[4]; } H, L;
    H.u[0]=h0|(h1<<16); H.u[1]=h2|(h3<<16); H.u[2]=h4|(h5<<16); H.u[3]=h6|(h7<<16);
    L.u[0]=l0|(l1<<16); L.u[1]=l2|(l3<<16); L.u[2]=l4|(l5<<16); L.u[3]=l6|(l7<<16);
    Split8 r; r.hi = H.v; r.lo = L.v; return r;
}

// ---- prep: codebook -> fragment-major split-bf16 image (4KB per 16-code chunk) ----
// chunk layout: [B0][B1] = hi feats 0..31/32..63, [B2][B3] = lo; lane(j,g)=g*16+j
// holds code j, features g*8..g*8+7.
__global__ __launch_bounds__(256) void vq_prep(const float* __restrict__ cb,
                                               uint8_t* __restrict__ stage,
                                               float* __restrict__ negcn) {
    int t = blockIdx.x * 256 + threadIdx.x;     // 0..32767, one per 8 floats
    int code = t >> 3, oct = t & 7;
    const float4* cp = (const float4*)(cb + (size_t)code * Dn + oct * 8);
    float4 f0 = cp[0], f1 = cp[1];
    Split8 s = split8(f0, f1);
    int j = code & 15, cc = code >> 4;
    uint8_t* base = stage + (size_t)cc * 4096;
    int dsto = (((oct & 3) * 16 + j) << 4) + ((oct & 4) ? 1024 : 0);
    *(bf16x8*)(base + dsto)        = s.hi;
    *(bf16x8*)(base + 2048 + dsto) = s.lo;
    float n = f0.x*f0.x + f0.y*f0.y + f0.z*f0.z + f0.w*f0.w
            + f1.x*f1.x + f1.y*f1.y + f1.z*f1.z + f1.w*f1.w;
    n += __shfl_xor(n, 1); n += __shfl_xor(n, 2); n += __shfl_xor(n, 4);
    if (oct == 0) negcn[code] = -0.5f * n;
}

__global__ void vq_zero(float* __restrict__ loss_acc, int* __restrict__ flag_cnt) {
    *loss_acc = 0.0f; *flag_cnt = 0;
}

// 1024 blocks x 256 thr; 4 waves: (row-tile = w>>1) x (K-half = w&1); 64 rows/wave.
__global__ __launch_bounds__(256, 4) void vq_main(
    const float* __restrict__ x, const uint8_t* __restrict__ stage,
    const float* __restrict__ negcn, const float* __restrict__ cb,
    float* __restrict__ out, float* __restrict__ loss_acc,
    int* __restrict__ flag_cnt, int* __restrict__ flag_rows) {

    __shared__ float sneg[Kn];                       // -0.5|c|^2
    __shared__ float smv1[4][64], smv2[4][64];
    __shared__ int   smk[4][64];
    __shared__ int   sres[128];

    const int tid = threadIdx.x;
    const int lane = tid & 63, w = tid >> 6;
    const int g = lane >> 4, j = lane & 15;
    const int kh = w & 1;                // K-half
    const int cstart = kh * HCHUNK;

    #pragma unroll
    for (int i = 0; i < 16; ++i) sneg[i*256 + tid] = negcn[i*256 + tid];

    // A fragments: 4 sub-tiles of 16 rows (A layout: row=lane&15, k=(lane>>4)*8+e)
    const int rowbase = blockIdx.x * 128 + (w >> 1) * 64;
    bf16x8 ah[4][2], al[4][2];
    #pragma unroll
    for (int t = 0; t < 4; ++t) {
        const float* xr = x + (size_t)(rowbase + t*16 + j) * Dn + g*8;
        Split8 s0 = split8(*(const float4*)xr,        *(const float4*)(xr + 4));
        Split8 s1 = split8(*(const float4*)(xr + 32), *(const float4*)(xr + 36));
        ah[t][0] = s0.hi; al[t][0] = s0.lo;
        ah[t][1] = s1.hi; al[t][1] = s1.lo;
    }

    // packed top-2: score low byte carries the chunk index (b1 >= b2 invariant)
    float b1[16], b2[16];
    #pragma unroll
    for (int s = 0; s < 16; ++s) { b1[s] = -3.4e38f; b2[s] = -3.4e38f; }

    const uint8_t* sp = stage + (lane << 4);
    __syncthreads();     // sneg visible

    #pragma unroll 1
    for (int c = cstart; c < cstart + HCHUNK; ++c) {
        const uint8_t* bp = sp + ((size_t)c << 12);
        // phase 1: ch (features 0..31 in bb0, 32..63 in bb1)
        bf16x8 bb0 = *(const bf16x8*)(bp);
        bf16x8 bb1 = *(const bf16x8*)(bp + 1024);
        float nc = sneg[(c << 4) + j];
        f32x4 a0 = {nc,nc,nc,nc}, a1 = {nc,nc,nc,nc};
        f32x4 a2 = {nc,nc,nc,nc}, a3 = {nc,nc,nc,nc};
        a0 = __builtin_amdgcn_mfma_f32_16x16x32_bf16(ah[0][0], bb0, a0, 0,0,0);
        a1 = __builtin_amdgcn_mfma_f32_16x16x32_bf16(ah[1][0], bb0, a1, 0,0,0);
        a2 = __builtin_amdgcn_mfma_f32_16x16x32_bf16(ah[2][0], bb0, a2, 0,0,0);
        a3 = __builtin_amdgcn_mfma_f32_16x16x32_bf16(ah[3][0], bb0, a3, 0,0,0);
        a0 = __builtin_amdgcn_mfma_f32_16x16x32_bf16(al[0][0], bb0, a0, 0,0,0);
        a1 = __builtin_amdgcn_mfma_f32_16x16x32_bf16(al[1][0], bb0, a1, 0,0,0);
        a2 = __builtin_amdgcn_mfma_f32_16x16x32_bf16(al[2][0], bb0, a2, 0,0,0);
        a3 = __builtin_amdgcn_mfma_f32_16x16x32_bf16(al[3][0], bb0, a3, 0,0,0);
        a0 = __builtin_amdgcn_mfma_f32_16x16x32_bf16(ah[0][1], bb1, a0, 0,0,0);
        a1 = __builtin_amdgcn_mfma_f32_16x16x32_bf16(ah[1][1], bb1, a1, 0,0,0);
        a2 = __builtin_amdgcn_mfma_f32_16x16x32_bf16(ah[2][1], bb1, a2, 0,0,0);
        a3 = __builtin_amdgcn_mfma_f32_16x16x32_bf16(ah[3][1], bb1, a3, 0,0,0);
        a0 = __builtin_amdgcn_mfma_f32_16x16x32_bf16(al[0][1], bb1, a0, 0,0,0);
        a1 = __builtin_amdgcn_mfma_f32_16x16x32_bf16(al[1][1], bb1, a1, 0,0,0);
        a2 = __builtin_amdgcn_mfma_f32_16x16x32_bf16(al[2][1], bb1, a2, 0,0,0);
        a3 = __builtin_amdgcn_mfma_f32_16x16x32_bf16(al[3][1], bb1, a3, 0,0,0);
        // phase 2: cl reuses the same 8 B registers
        bb0 = *(const bf16x8*)(bp + 2048);
        bb1 = *(const bf16x8*)(bp + 3072);
        a0 = __builtin_amdgcn_mfma_f32_16x16x32_bf16(ah[0][0], bb0, a0, 0,0,0);
        a1 = __builtin_amdgcn_mfma_f32_16x16x32_bf16(ah[1][0], bb0, a1, 0,0,0);
        a2 = __builtin_amdgcn_mfma_f32_16x16x32_bf16(ah[2][0], bb0, a2, 0,0,0);
        a3 = __builtin_amdgcn_mfma_f32_16x16x32_bf16(ah[3][0], bb0, a3, 0,0,0);
        a0 = __builtin_amdgcn_mfma_f32_16x16x32_bf16(ah[0][1], bb1, a0, 0,0,0);
        a1 = __builtin_amdgcn_mfma_f32_16x16x32_bf16(ah[1][1], bb1, a1, 0,0,0);
        a2 = __builtin_amdgcn_mfma_f32_16x16x32_bf16(ah[2][1], bb1, a2, 0,0,0);
        a3 = __builtin_amdgcn_mfma_f32_16x16x32_bf16(ah[3][1], bb1, a3, 0,0,0);
        // TOP2: v_perm splices chunk idx into the score's low mantissa byte
        const uint32_t cc = (uint32_t)(c & 0xFF);
        #pragma unroll
        for (int q = 0; q < 4; ++q) {
            float vp = __uint_as_float(__builtin_amdgcn_perm(__float_as_uint(a0[q]), cc, 0x07060500u));
            float ob = b1[q];
            b2[q] = __builtin_amdgcn_fmed3f(vp, ob, b2[q]);
            b1[q] = fmaxf(ob, vp);
        }
        #pragma unroll
        for (int q = 0; q < 4; ++q) {
            float vp = __uint_as_float(__builtin_amdgcn_perm(__float_as_uint(a1[q]), cc, 0x07060500u));
            float ob = b1[4+q];
            b2[4+q] = __builtin_amdgcn_fmed3f(vp, ob, b2[4+q]);
            b1[4+q] = fmaxf(ob, vp);
        }
        #pragma unroll
        for (int q = 0; q < 4; ++q) {
            float vp = __uint_as_float(__builtin_amdgcn_perm(__float_as_uint(a2[q]), cc, 0x07060500u));
            float ob = b1[8+q];
            b2[8+q] = __builtin_amdgcn_fmed3f(vp, ob, b2[8+q]);
            b1[8+q] = fmaxf(ob, vp);
        }
        #pragma unroll
        for (int q = 0; q < 4; ++q) {
            float vp = __uint_as_float(__builtin_amdgcn_perm(__float_as_uint(a3[q]), cc, 0x07060500u));
            float ob = b1[12+q];
            b2[12+q] = __builtin_amdgcn_fmed3f(vp, ob, b2[12+q]);
            b1[12+q] = fmaxf(ob, vp);
        }
    }

    // per-row merge across the 16 code-lanes (D layout: row=(lane>>4)*4+q, col=lane&15)
    #pragma unroll
    for (int s = 0; s < 16; ++s) {
        float v1 = b1[s], v2 = b2[s];
        int kk = (int)((__float_as_uint(v1) & 0xFFu) << 4) + j;   // c*16 + j
        #pragma unroll
        for (int m = 1; m < 16; m <<= 1) {
            float p1 = __shfl_xor(v1, m);
            float p2 = __shfl_xor(v2, m);
            int pk = __shfl_xor(kk, m);
            v2 = fmaxf(fmaxf(v2, p2), fminf(v1, p1));
            bool take = (p1 > v1) || ((p1 == v1) && (pk < kk));
            v1 = take ? p1 : v1;
            kk = take ? pk : kk;
        }
        if (j == 0) {
            int row = (s >> 2)*16 + g*4 + (s & 3);   // 0..63 within wave
            smv1[w][row] = v1; smv2[w][row] = v2; smk[w][row] = kk;
        }
    }
    __syncthreads();

    // cross-K-half merge (disjoint k-ranges; near-ties all fall under TAU -> cleanup)
    if (tid < 128) {
        int rt = tid >> 6, r = tid & 63;
        int wa = rt * 2, wb = wa + 1;
        float v1a = smv1[wa][r], v2a = smv2[wa][r];
        float v1b = smv1[wb][r], v2b = smv2[wb][r];
        int   ka  = smk[wa][r],  kb  = smk[wb][r];
        bool take = v1b > v1a;
        float m1 = take ? v1b : v1a;
        int   kk = take ? kb  : ka;
        float m2 = fmaxf(fmaxf(v2a, v2b), fminf(v1a, v1b));
        int flag = ((m1 - m2) < TAU_S) ? (int)0x80000000 : 0;
        sres[tid] = kk | flag;
    }
    __syncthreads();

    // epilogue: fully coalesced; f enumerates (row, float4) pairs; 128 rows/block
    float ls = 0.f;
    const size_t blockrow = (size_t)blockIdx.x * 128;
    #pragma unroll 1
    for (int it = 0; it < 8; ++it) {
        int f = it * 256 + tid;
        int r = f >> 4, q = f & 15;
        int pk = sres[r];
        int idx = pk & 0x7FFFFFFF;
        bool flagged = pk < 0;
        size_t grow = blockrow + r;
        float4 xx = ((const float4*)(x + grow * Dn))[q];
        float4 qq = ((const float4*)(cb + (size_t)idx * Dn))[q];
        float dx = qq.x - xx.x, dy = qq.y - xx.y, dz = qq.z - xx.z, dw = qq.w - xx.w;
        float4 o; o.x = xx.x + dx; o.y = xx.y + dy; o.z = xx.z + dz; o.w = xx.w + dw;
        ((float4*)(out + grow * Dn))[q] = o;
        if (flagged) {
            if (q == 0) { int p = atomicAdd(flag_cnt, 1); flag_rows[p] = (int)grow; }
        } else {
            ls = fmaf(dx, dx, ls); ls = fmaf(dy, dy, ls);
            ls = fmaf(dz, dz, ls); ls = fmaf(dw, dw, ls);
        }
    }
    #pragma unroll
    for (int m = 1; m < 64; m <<= 1) ls += __shfl_xor(ls, m);
    if (lane == 0) atomicAdd(loss_acc, ls);
}

// fp64 full rescan of flagged rows, 8 rows per block-iteration (codebook read shared).
__global__ __launch_bounds__(256) void vq_cleanup(
    const float* __restrict__ x, const float* __restrict__ cb,
    const int* __restrict__ flag_cnt, const int* __restrict__ flag_rows,
    float* __restrict__ out, float* __restrict__ loss_acc) {
    __shared__ double sxd[8][Dn];
    __shared__ double swb[8][4];
    __shared__ int    swi[8][4];
    const int tid = threadIdx.x;
    const int n = *flag_cnt;

    for (int it = blockIdx.x; it * 8 < n; it += gridDim.x) {
        const int base = it * 8;
        const int nr = min(8, n - base);
        __syncthreads();   // protect sxd/swb from previous iteration readers
        {
            int rr = tid >> 5, e = tid & 31;
            int row = flag_rows[base + ((rr < nr) ? rr : 0)];
            sxd[rr][e]      = (double)x[(size_t)row * Dn + e];
            sxd[rr][e + 32] = (double)x[(size_t)row * Dn + e + 32];
        }
        __syncthreads();

        double best[8]; int bidx[8];
        #pragma unroll
        for (int r2 = 0; r2 < 8; ++r2) { best[r2] = 1.0e300; bidx[r2] = 0x7FFFFFFF; }

        #pragma unroll 1
        for (int i = 0; i < Kn / 256; ++i) {          // 16 codes per thread
            const int k = i * 256 + tid;
            const float* c4 = cb + (size_t)k * Dn;
            double cn = 0.0;
            double d0=0.0,d1=0.0,d2=0.0,d3=0.0,d4=0.0,d5=0.0,d6=0.0,d7=0.0;
            #pragma unroll 8
            for (int e = 0; e < Dn; ++e) {
                double ce = (double)c4[e];
                cn = fma(ce, ce, cn);
                d0 = fma(ce, sxd[0][e], d0);
                d1 = fma(ce, sxd[1][e], d1);
                d2 = fma(ce, sxd[2][e], d2);
                d3 = fma(ce, sxd[3][e], d3);
                d4 = fma(ce, sxd[4][e], d4);
                d5 = fma(ce, sxd[5][e], d5);
                d6 = fma(ce, sxd[6][e], d6);
                d7 = fma(ce, sxd[7][e], d7);
            }
            double dd[8] = { cn - 2.0*d0, cn - 2.0*d1, cn - 2.0*d2, cn - 2.0*d3,
                             cn - 2.0*d4, cn - 2.0*d5, cn - 2.0*d6, cn - 2.0*d7 };
            #pragma unroll
            for (int r2 = 0; r2 < 8; ++r2)
                if (dd[r2] < best[r2] || (dd[r2] == best[r2] && k < bidx[r2])) {
                    best[r2] = dd[r2]; bidx[r2] = k;
                }
        }
        // wave argmin then cross-wave merge (first-occurrence ties)
        #pragma unroll
        for (int r2 = 0; r2 < 8; ++r2) {
            double bb = best[r2]; int bi = bidx[r2];
            #pragma unroll
            for (int m = 1; m < 64; m <<= 1) {
                double pb = __shfl_xor(bb, m);
                int    pi = __shfl_xor(bi, m);
                if (pb < bb || (pb == bb && pi < bi)) { bb = pb; bi = pi; }
            }
            if ((tid & 63) == 0) { swb[r2][tid >> 6] = bb; swi[r2][tid >> 6] = bi; }
        }
        __syncthreads();
        if (tid < 8) {
            double fb = swb[tid][0]; int fi = swi[tid][0];
            #pragma unroll
            for (int wv = 1; wv < 4; ++wv) {
                double pb = swb[tid][wv]; int pi = swi[tid][wv];
                if (pb < fb || (pb == fb && pi < fi)) { fb = pb; fi = pi; }
            }
            swi[tid][0] = fi;
        }
        __syncthreads();

        if (tid < 128) {
            int r2 = tid >> 4, q = tid & 15;
            if (r2 < nr) {
                int row = flag_rows[base + r2];
                int fi  = swi[r2][0];
                float4 xx = ((const float4*)(x + (size_t)row * Dn))[q];
                float4 qq = ((const float4*)(cb + (size_t)fi * Dn))[q];
                float dx = qq.x - xx.x, dy = qq.y - xx.y, dz = qq.z - xx.z, dw = qq.w - xx.w;
                float4 o; o.x = xx.x + dx; o.y = xx.y + dy; o.z = xx.z + dz; o.w = xx.w + dw;
                ((float4*)(out + (size_t)row * Dn))[q] = o;
                float ls = dx*dx + dy*dy + dz*dz + dw*dw;
                ls += __shfl_xor(ls, 1); ls += __shfl_xor(ls, 2);
                ls += __shfl_xor(ls, 4); ls += __shfl_xor(ls, 8);
                if (q == 0) atomicAdd(loss_acc, ls);
            }
        }
    }
}

__global__ void vq_final(float* __restrict__ loss_acc) {
    *loss_acc = *loss_acc * (1.25f / (float)(Bn * Dn));
}

extern "C" void kernel_launch(void* const* d_in, const int* in_sizes, int n_in,
                              void* d_out, int out_size, void* d_ws, size_t ws_size,
                              hipStream_t stream) {
    const float* x  = (const float*)d_in[0];
    const float* cb = (const float*)d_in[1];
    float* out  = (float*)d_out;
    float* loss = out + (size_t)Bn * Dn;

    // ws layout: [negcn 16KB][stage 1MB][flag_cnt 4B][flag_rows 512KB]
    uint8_t* wsb = (uint8_t*)d_ws;
    float*   negcn     = (float*)wsb;
    uint8_t* stage     = wsb + 16384;
    int*     flag_cnt  = (int*)(wsb + 16384 + (size_t)NCHUNK * 4096);
    int*     flag_rows = flag_cnt + 1;

    vq_prep<<<128, 256, 0, stream>>>(cb, stage, negcn);
    vq_zero<<<1, 1, 0, stream>>>(loss, flag_cnt);
    vq_main<<<Bn / 128, 256, 0, stream>>>(x, stage, negcn, cb, out, loss, flag_cnt, flag_rows);
    vq_cleanup<<<512, 256, 0, stream>>>(x, cb, flag_cnt, flag_rows, out, loss);
    vq_final<<<1, 1, 0, stream>>>(loss);
}

// Round 13
// 274.234 us; speedup vs baseline: 2.9885x; 1.2116x over previous
//
#include <hip/hip_runtime.h>
#include <stdint.h>

// VQ: B=131072 rows, K=4096 codes, D=64, fp32 in/out.
// out = [B*D floats quantized_st][1 float loss]
//
// bf16 split-precision MFMA distance search (3-product exact-split), top-2
// tracking with the CHUNK INDEX PACKED into the score's low mantissa byte
// (v_perm splice), fp64 rescan of rows whose packed score gap < TAU.
// K-SPLIT r9 geometry: 64 rows/wave, waves 2t/2t+1 share rows, disjoint K
// halves, 1024 blocks. r13: ROLLING PHASE PREFETCH — per chunk, issue all 4
// B-loads (lo(c), hi(c+1)) up front into dead buffers, cover with the 16
// hi-MFMAs / 8 lo-MFMAs. B-state 24 regs: footprint ~146 fits (256,3)'s
// 170-reg cap -> 3 waves/SIMD AND r9-class latency hiding (r9: hid latency
// at 2 waves; r12: 3.3 waves but 2 serial L2 waits/chunk -> both beaten).
constexpr int Bn = 131072, Kn = 4096, Dn = 64;
constexpr int NCHUNK = 256;          // K / 16 codes per chunk (c fits in 8 bits)
constexpr int HCHUNK = 128;          // chunks per K-half
constexpr float TAU_S = 0.015f;      // covers split ~5e-3 + pack ~4e-3 per gap

typedef short bf16x8 __attribute__((ext_vector_type(8)));
typedef float f32x4  __attribute__((ext_vector_type(4)));

__device__ __forceinline__ uint32_t rneb(float f) {           // bf16 RNE bits
    uint32_t u = __float_as_uint(f);
    return (u + 0x7FFFu + ((u >> 16) & 1u)) >> 16;
}
__device__ __forceinline__ float bfval(uint32_t b) { return __uint_as_float(b << 16); }

struct Split8 { bf16x8 hi, lo; };
__device__ __forceinline__ Split8 split8(float4 a, float4 b) {
    uint32_t h0=rneb(a.x),h1=rneb(a.y),h2=rneb(a.z),h3=rneb(a.w);
    uint32_t h4=rneb(b.x),h5=rneb(b.y),h6=rneb(b.z),h7=rneb(b.w);
    uint32_t l0=rneb(a.x-bfval(h0)), l1=rneb(a.y-bfval(h1));
    uint32_t l2=rneb(a.z-bfval(h2)), l3=rneb(a.w-bfval(h3));
    uint32_t l4=rneb(b.x-bfval(h4)), l5=rneb(b.y-bfval(h5));
    uint32_t l6=rneb(b.z-bfval(h6)), l7=rneb(b.w-bfval(h7));
    union { bf16x8 v; uint32_t u[4]; } H, L;
    H.u[0]=h0|(h1<<16); H.u[1]=h2|(h3<<16); H.u[2]=h4|(h5<<16); H.u[3]=h6|(h7<<16);
    L.u[0]=l0|(l1<<16); L.u[1]=l2|(l3<<16); L.u[2]=l4|(l5<<16); L.u[3]=l6|(l7<<16);
    Split8 r; r.hi = H.v; r.lo = L.v; return r;
}

// ---- prep: codebook -> fragment-major split-bf16 image (4KB per 16-code chunk) ----
// chunk layout: [B0][B1] = hi feats 0..31/32..63, [B2][B3] = lo; lane(j,g)=g*16+j
// holds code j, features g*8..g*8+7.
__global__ __launch_bounds__(256) void vq_prep(const float* __restrict__ cb,
                                               uint8_t* __restrict__ stage,
                                               float* __restrict__ negcn) {
    int t = blockIdx.x * 256 + threadIdx.x;     // 0..32767, one per 8 floats
    int code = t >> 3, oct = t & 7;
    const float4* cp = (const float4*)(cb + (size_t)code * Dn + oct * 8);
    float4 f0 = cp[0], f1 = cp[1];
    Split8 s = split8(f0, f1);
    int j = code & 15, cc = code >> 4;
    uint8_t* base = stage + (size_t)cc * 4096;
    int dsto = (((oct & 3) * 16 + j) << 4) + ((oct & 4) ? 1024 : 0);
    *(bf16x8*)(base + dsto)        = s.hi;
    *(bf16x8*)(base + 2048 + dsto) = s.lo;
    float n = f0.x*f0.x + f0.y*f0.y + f0.z*f0.z + f0.w*f0.w
            + f1.x*f1.x + f1.y*f1.y + f1.z*f1.z + f1.w*f1.w;
    n += __shfl_xor(n, 1); n += __shfl_xor(n, 2); n += __shfl_xor(n, 4);
    if (oct == 0) negcn[code] = -0.5f * n;
}

__global__ void vq_zero(float* __restrict__ loss_acc, int* __restrict__ flag_cnt) {
    *loss_acc = 0.0f; *flag_cnt = 0;
}

// 1024 blocks x 256 thr; 4 waves: (row-tile = w>>1) x (K-half = w&1); 64 rows/wave.
__global__ __launch_bounds__(256, 3) void vq_main(
    const float* __restrict__ x, const uint8_t* __restrict__ stage,
    const float* __restrict__ negcn, const float* __restrict__ cb,
    float* __restrict__ out, float* __restrict__ loss_acc,
    int* __restrict__ flag_cnt, int* __restrict__ flag_rows) {

    __shared__ float sneg[Kn];                       // -0.5|c|^2
    __shared__ float smv1[4][64], smv2[4][64];
    __shared__ int   smk[4][64];
    __shared__ int   sres[128];

    const int tid = threadIdx.x;
    const int lane = tid & 63, w = tid >> 6;
    const int g = lane >> 4, j = lane & 15;
    const int kh = w & 1;                // K-half
    const int cstart = kh * HCHUNK;
    const int cend = cstart + HCHUNK;

    #pragma unroll
    for (int i = 0; i < 16; ++i) sneg[i*256 + tid] = negcn[i*256 + tid];

    // A fragments: 4 sub-tiles of 16 rows (A layout: row=lane&15, k=(lane>>4)*8+e)
    const int rowbase = blockIdx.x * 128 + (w >> 1) * 64;
    bf16x8 ah[4][2], al[4][2];
    #pragma unroll
    for (int t = 0; t < 4; ++t) {
        const float* xr = x + (size_t)(rowbase + t*16 + j) * Dn + g*8;
        Split8 s0 = split8(*(const float4*)xr,        *(const float4*)(xr + 4));
        Split8 s1 = split8(*(const float4*)(xr + 32), *(const float4*)(xr + 36));
        ah[t][0] = s0.hi; al[t][0] = s0.lo;
        ah[t][1] = s1.hi; al[t][1] = s1.lo;
    }

    // packed top-2: score low byte carries the chunk index (b1 >= b2 invariant)
    float b1[16], b2[16];
    #pragma unroll
    for (int s = 0; s < 16; ++s) { b1[s] = -3.4e38f; b2[s] = -3.4e38f; }

    const uint8_t* sp = stage + (lane << 4);
    // prologue: hi(cstart) into buffer set 0
    bf16x8 h00 = *(const bf16x8*)(sp + ((size_t)cstart << 12));
    bf16x8 h01 = *(const bf16x8*)(sp + ((size_t)cstart << 12) + 1024);
    bf16x8 h10 = {}, h11 = {};
    __syncthreads();     // sneg visible

#define TOP2(ACC, BASE)                                                       \
    _Pragma("unroll")                                                         \
    for (int q = 0; q < 4; ++q) {                                             \
        float vp = __uint_as_float(__builtin_amdgcn_perm(                     \
            __float_as_uint(ACC[q]), cc_, 0x07060500u));                      \
        float ob = b1[(BASE)+q];                                              \
        b2[(BASE)+q] = __builtin_amdgcn_fmed3f(vp, ob, b2[(BASE)+q]);         \
        b1[(BASE)+q] = fmaxf(ob, vp);                                         \
    }

// HB0/HB1: current hi fragments (already resident). HN0/HN1: buffer for hi(c+1).
#define CHUNK_BODY(HB0, HB1, HN0, HN1, C)                                     \
    {                                                                         \
        const int c_ = (C);                                                   \
        const uint32_t cc_ = (uint32_t)(c_ & 0xFF);                           \
        const uint8_t* bp = sp + ((size_t)c_ << 12);                          \
        const int cn_ = (c_ + 1 < cend) ? (c_ + 1) : c_;                      \
        const uint8_t* np = sp + ((size_t)cn_ << 12);                         \
        /* issue all 4 loads up front into dead buffers */                    \
        bf16x8 L0 = *(const bf16x8*)(bp + 2048);                              \
        bf16x8 L1 = *(const bf16x8*)(bp + 3072);                              \
        HN0 = *(const bf16x8*)(np);                                           \
        HN1 = *(const bf16x8*)(np + 1024);                                    \
        float nc = sneg[(c_ << 4) + j];                                       \
        f32x4 a0 = {nc,nc,nc,nc}, a1 = {nc,nc,nc,nc};                         \
        f32x4 a2 = {nc,nc,nc,nc}, a3 = {nc,nc,nc,nc};                         \
        __builtin_amdgcn_s_setprio(1);                                        \
        a0 = __builtin_amdgcn_mfma_f32_16x16x32_bf16(ah[0][0], HB0, a0, 0,0,0);\
        a1 = __builtin_amdgcn_mfma_f32_16x16x32_bf16(ah[1][0], HB0, a1, 0,0,0);\
        a2 = __builtin_amdgcn_mfma_f32_16x16x32_bf16(ah[2][0], HB0, a2, 0,0,0);\
        a3 = __builtin_amdgcn_mfma_f32_16x16x32_bf16(ah[3][0], HB0, a3, 0,0,0);\
        a0 = __builtin_amdgcn_mfma_f32_16x16x32_bf16(al[0][0], HB0, a0, 0,0,0);\
        a1 = __builtin_amdgcn_mfma_f32_16x16x32_bf16(al[1][0], HB0, a1, 0,0,0);\
        a2 = __builtin_amdgcn_mfma_f32_16x16x32_bf16(al[2][0], HB0, a2, 0,0,0);\
        a3 = __builtin_amdgcn_mfma_f32_16x16x32_bf16(al[3][0], HB0, a3, 0,0,0);\
        a0 = __builtin_amdgcn_mfma_f32_16x16x32_bf16(ah[0][1], HB1, a0, 0,0,0);\
        a1 = __builtin_amdgcn_mfma_f32_16x16x32_bf16(ah[1][1], HB1, a1, 0,0,0);\
        a2 = __builtin_amdgcn_mfma_f32_16x16x32_bf16(ah[2][1], HB1, a2, 0,0,0);\
        a3 = __builtin_amdgcn_mfma_f32_16x16x32_bf16(ah[3][1], HB1, a3, 0,0,0);\
        a0 = __builtin_amdgcn_mfma_f32_16x16x32_bf16(al[0][1], HB1, a0, 0,0,0);\
        a1 = __builtin_amdgcn_mfma_f32_16x16x32_bf16(al[1][1], HB1, a1, 0,0,0);\
        a2 = __builtin_amdgcn_mfma_f32_16x16x32_bf16(al[2][1], HB1, a2, 0,0,0);\
        a3 = __builtin_amdgcn_mfma_f32_16x16x32_bf16(al[3][1], HB1, a3, 0,0,0);\
        /* lo phase: xh . cl */                                               \
        a0 = __builtin_amdgcn_mfma_f32_16x16x32_bf16(ah[0][0], L0, a0, 0,0,0);\
        a1 = __builtin_amdgcn_mfma_f32_16x16x32_bf16(ah[1][0], L0, a1, 0,0,0);\
        a2 = __builtin_amdgcn_mfma_f32_16x16x32_bf16(ah[2][0], L0, a2, 0,0,0);\
        a3 = __builtin_amdgcn_mfma_f32_16x16x32_bf16(ah[3][0], L0, a3, 0,0,0);\
        a0 = __builtin_amdgcn_mfma_f32_16x16x32_bf16(ah[0][1], L1, a0, 0,0,0);\
        a1 = __builtin_amdgcn_mfma_f32_16x16x32_bf16(ah[1][1], L1, a1, 0,0,0);\
        a2 = __builtin_amdgcn_mfma_f32_16x16x32_bf16(ah[2][1], L1, a2, 0,0,0);\
        a3 = __builtin_amdgcn_mfma_f32_16x16x32_bf16(ah[3][1], L1, a3, 0,0,0);\
        __builtin_amdgcn_s_setprio(0);                                        \
        TOP2(a0, 0) TOP2(a1, 4) TOP2(a2, 8) TOP2(a3, 12)                      \
    }

    #pragma unroll 1
    for (int c4 = cstart; c4 < cend; c4 += 2) {
        CHUNK_BODY(h00, h01, h10, h11, c4)
        CHUNK_BODY(h10, h11, h00, h01, c4 + 1)
    }
#undef CHUNK_BODY
#undef TOP2

    // per-row merge across the 16 code-lanes (D layout: row=(lane>>4)*4+q, col=lane&15)
    #pragma unroll
    for (int s = 0; s < 16; ++s) {
        float v1 = b1[s], v2 = b2[s];
        int kk = (int)((__float_as_uint(v1) & 0xFFu) << 4) + j;   // c*16 + j
        #pragma unroll
        for (int m = 1; m < 16; m <<= 1) {
            float p1 = __shfl_xor(v1, m);
            float p2 = __shfl_xor(v2, m);
            int pk = __shfl_xor(kk, m);
            v2 = fmaxf(fmaxf(v2, p2), fminf(v1, p1));
            bool take = (p1 > v1) || ((p1 == v1) && (pk < kk));
            v1 = take ? p1 : v1;
            kk = take ? pk : kk;
        }
        if (j == 0) {
            int row = (s >> 2)*16 + g*4 + (s & 3);   // 0..63 within wave
            smv1[w][row] = v1; smv2[w][row] = v2; smk[w][row] = kk;
        }
    }
    __syncthreads();

    // cross-K-half merge (disjoint k-ranges; near-ties all fall under TAU -> cleanup)
    if (tid < 128) {
        int rt = tid >> 6, r = tid & 63;
        int wa = rt * 2, wb = wa + 1;
        float v1a = smv1[wa][r], v2a = smv2[wa][r];
        float v1b = smv1[wb][r], v2b = smv2[wb][r];
        int   ka  = smk[wa][r],  kb  = smk[wb][r];
        bool take = v1b > v1a;
        float m1 = take ? v1b : v1a;
        int   kk = take ? kb  : ka;
        float m2 = fmaxf(fmaxf(v2a, v2b), fminf(v1a, v1b));
        int flag = ((m1 - m2) < TAU_S) ? (int)0x80000000 : 0;
        sres[tid] = kk | flag;
    }
    __syncthreads();

    // epilogue: fully coalesced; f enumerates (row, float4) pairs; 128 rows/block
    float ls = 0.f;
    const size_t blockrow = (size_t)blockIdx.x * 128;
    #pragma unroll 1
    for (int it = 0; it < 8; ++it) {
        int f = it * 256 + tid;
        int r = f >> 4, q = f & 15;
        int pk = sres[r];
        int idx = pk & 0x7FFFFFFF;
        bool flagged = pk < 0;
        size_t grow = blockrow + r;
        float4 xx = ((const float4*)(x + grow * Dn))[q];
        float4 qq = ((const float4*)(cb + (size_t)idx * Dn))[q];
        float dx = qq.x - xx.x, dy = qq.y - xx.y, dz = qq.z - xx.z, dw = qq.w - xx.w;
        float4 o; o.x = xx.x + dx; o.y = xx.y + dy; o.z = xx.z + dz; o.w = xx.w + dw;
        ((float4*)(out + grow * Dn))[q] = o;
        if (flagged) {
            if (q == 0) { int p = atomicAdd(flag_cnt, 1); flag_rows[p] = (int)grow; }
        } else {
            ls = fmaf(dx, dx, ls); ls = fmaf(dy, dy, ls);
            ls = fmaf(dz, dz, ls); ls = fmaf(dw, dw, ls);
        }
    }
    #pragma unroll
    for (int m = 1; m < 64; m <<= 1) ls += __shfl_xor(ls, m);
    if (lane == 0) atomicAdd(loss_acc, ls);
}

// fp64 full rescan of flagged rows, 8 rows per block-iteration (codebook read shared).
__global__ __launch_bounds__(256) void vq_cleanup(
    const float* __restrict__ x, const float* __restrict__ cb,
    const int* __restrict__ flag_cnt, const int* __restrict__ flag_rows,
    float* __restrict__ out, float* __restrict__ loss_acc) {
    __shared__ double sxd[8][Dn];
    __shared__ double swb[8][4];
    __shared__ int    swi[8][4];
    const int tid = threadIdx.x;
    const int n = *flag_cnt;

    for (int it = blockIdx.x; it * 8 < n; it += gridDim.x) {
        const int base = it * 8;
        const int nr = min(8, n - base);
        __syncthreads();   // protect sxd/swb from previous iteration readers
        {
            int rr = tid >> 5, e = tid & 31;
            int row = flag_rows[base + ((rr < nr) ? rr : 0)];
            sxd[rr][e]      = (double)x[(size_t)row * Dn + e];
            sxd[rr][e + 32] = (double)x[(size_t)row * Dn + e + 32];
        }
        __syncthreads();

        double best[8]; int bidx[8];
        #pragma unroll
        for (int r2 = 0; r2 < 8; ++r2) { best[r2] = 1.0e300; bidx[r2] = 0x7FFFFFFF; }

        #pragma unroll 1
        for (int i = 0; i < Kn / 256; ++i) {          // 16 codes per thread
            const int k = i * 256 + tid;
            const float* c4 = cb + (size_t)k * Dn;
            double cn = 0.0;
            double d0=0.0,d1=0.0,d2=0.0,d3=0.0,d4=0.0,d5=0.0,d6=0.0,d7=0.0;
            #pragma unroll 8
            for (int e = 0; e < Dn; ++e) {
                double ce = (double)c4[e];
                cn = fma(ce, ce, cn);
                d0 = fma(ce, sxd[0][e], d0);
                d1 = fma(ce, sxd[1][e], d1);
                d2 = fma(ce, sxd[2][e], d2);
                d3 = fma(ce, sxd[3][e], d3);
                d4 = fma(ce, sxd[4][e], d4);
                d5 = fma(ce, sxd[5][e], d5);
                d6 = fma(ce, sxd[6][e], d6);
                d7 = fma(ce, sxd[7][e], d7);
            }
            double dd[8] = { cn - 2.0*d0, cn - 2.0*d1, cn - 2.0*d2, cn - 2.0*d3,
                             cn - 2.0*d4, cn - 2.0*d5, cn - 2.0*d6, cn - 2.0*d7 };
            #pragma unroll
            for (int r2 = 0; r2 < 8; ++r2)
                if (dd[r2] < best[r2] || (dd[r2] == best[r2] && k < bidx[r2])) {
                    best[r2] = dd[r2]; bidx[r2] = k;
                }
        }
        // wave argmin then cross-wave merge (first-occurrence ties)
        #pragma unroll
        for (int r2 = 0; r2 < 8; ++r2) {
            double bb = best[r2]; int bi = bidx[r2];
            #pragma unroll
            for (int m = 1; m < 64; m <<= 1) {
                double pb = __shfl_xor(bb, m);
                int    pi = __shfl_xor(bi, m);
                if (pb < bb || (pb == bb && pi < bi)) { bb = pb; bi = pi; }
            }
            if ((tid & 63) == 0) { swb[r2][tid >> 6] = bb; swi[r2][tid >> 6] = bi; }
        }
        __syncthreads();
        if (tid < 8) {
            double fb = swb[tid][0]; int fi = swi[tid][0];
            #pragma unroll
            for (int wv = 1; wv < 4; ++wv) {
                double pb = swb[tid][wv]; int pi = swi[tid][wv];
                if (pb < fb || (pb == fb && pi < fi)) { fb = pb; fi = pi; }
            }
            swi[tid][0] = fi;
        }
        __syncthreads();

        if (tid < 128) {
            int r2 = tid >> 4, q = tid & 15;
            if (r2 < nr) {
                int row = flag_rows[base + r2];
                int fi  = swi[r2][0];
                float4 xx = ((const float4*)(x + (size_t)row * Dn))[q];
                float4 qq = ((const float4*)(cb + (size_t)fi * Dn))[q];
                float dx = qq.x - xx.x, dy = qq.y - xx.y, dz = qq.z - xx.z, dw = qq.w - xx.w;
                float4 o; o.x = xx.x + dx; o.y = xx.y + dy; o.z = xx.z + dz; o.w = xx.w + dw;
                ((float4*)(out + (size_t)row * Dn))[q] = o;
                float ls = dx*dx + dy*dy + dz*dz + dw*dw;
                ls += __shfl_xor(ls, 1); ls += __shfl_xor(ls, 2);
                ls += __shfl_xor(ls, 4); ls += __shfl_xor(ls, 8);
                if (q == 0) atomicAdd(loss_acc, ls);
            }
        }
    }
}

__global__ void vq_final(float* __restrict__ loss_acc) {
    *loss_acc = *loss_acc * (1.25f / (float)(Bn * Dn));
}

extern "C" void kernel_launch(void* const* d_in, const int* in_sizes, int n_in,
                              void* d_out, int out_size, void* d_ws, size_t ws_size,
                              hipStream_t stream) {
    const float* x  = (const float*)d_in[0];
    const float* cb = (const float*)d_in[1];
    float* out  = (float*)d_out;
    float* loss = out + (size_t)Bn * Dn;

    // ws layout: [negcn 16KB][stage 1MB][flag_cnt 4B][flag_rows 512KB]
    uint8_t* wsb = (uint8_t*)d_ws;
    float*   negcn     = (float*)wsb;
    uint8_t* stage     = wsb + 16384;
    int*     flag_cnt  = (int*)(wsb + 16384 + (size_t)NCHUNK * 4096);
    int*     flag_rows = flag_cnt + 1;

    vq_prep<<<128, 256, 0, stream>>>(cb, stage, negcn);
    vq_zero<<<1, 1, 0, stream>>>(loss, flag_cnt);
    vq_main<<<Bn / 128, 256, 0, stream>>>(x, stage, negcn, cb, out, loss, flag_cnt, flag_rows);
    vq_cleanup<<<512, 256, 0, stream>>>(x, cb, flag_cnt, flag_rows, out, loss);
    vq_final<<<1, 1, 0, stream>>>(loss);
}

// Round 14
// 273.536 us; speedup vs baseline: 2.9962x; 1.0026x over previous
//
#include <hip/hip_runtime.h>
#include <stdint.h>

// VQ: B=131072 rows, K=4096 codes, D=64, fp32 in/out.
// out = [B*D floats quantized_st][1 float loss]
//
// bf16 split-precision MFMA distance search (3-product exact-split), top-2
// tracking with the CHUNK INDEX PACKED into the score's low mantissa byte
// (v_perm splice), fp64 rescan of rows whose packed score gap < TAU.
// K-SPLIT r9 geometry: 64 rows/wave, waves 2t/2t+1 share rows, disjoint K
// halves, 1024 blocks. r13 rolling phase prefetch. r14: DEFERRED TOP2 —
// accumulators double-buffered (pA/pB); TOP2(c) issues AFTER MFMA(c+1) is
// in flight, so the top-2 VALU rides in the matrix-pipe shadow instead of
// stalling the wave between chunks (r9/r12/r13 all converged ~215-220 us
// with the pipe only ~45% busy because TOP2 was serial-after-MFMA).
constexpr int Bn = 131072, Kn = 4096, Dn = 64;
constexpr int NCHUNK = 256;          // K / 16 codes per chunk (c fits in 8 bits)
constexpr int HCHUNK = 128;          // chunks per K-half
constexpr float TAU_S = 0.015f;      // covers split ~5e-3 + pack ~4e-3 per gap

typedef short bf16x8 __attribute__((ext_vector_type(8)));
typedef float f32x4  __attribute__((ext_vector_type(4)));

__device__ __forceinline__ uint32_t rneb(float f) {           // bf16 RNE bits
    uint32_t u = __float_as_uint(f);
    return (u + 0x7FFFu + ((u >> 16) & 1u)) >> 16;
}
__device__ __forceinline__ float bfval(uint32_t b) { return __uint_as_float(b << 16); }

struct Split8 { bf16x8 hi, lo; };
__device__ __forceinline__ Split8 split8(float4 a, float4 b) {
    uint32_t h0=rneb(a.x),h1=rneb(a.y),h2=rneb(a.z),h3=rneb(a.w);
    uint32_t h4=rneb(b.x),h5=rneb(b.y),h6=rneb(b.z),h7=rneb(b.w);
    uint32_t l0=rneb(a.x-bfval(h0)), l1=rneb(a.y-bfval(h1));
    uint32_t l2=rneb(a.z-bfval(h2)), l3=rneb(a.w-bfval(h3));
    uint32_t l4=rneb(b.x-bfval(h4)), l5=rneb(b.y-bfval(h5));
    uint32_t l6=rneb(b.z-bfval(h6)), l7=rneb(b.w-bfval(h7));
    union { bf16x8 v; uint32_t u[4]; } H, L;
    H.u[0]=h0|(h1<<16); H.u[1]=h2|(h3<<16); H.u[2]=h4|(h5<<16); H.u[3]=h6|(h7<<16);
    L.u[0]=l0|(l1<<16); L.u[1]=l2|(l3<<16); L.u[2]=l4|(l5<<16); L.u[3]=l6|(l7<<16);
    Split8 r; r.hi = H.v; r.lo = L.v; return r;
}

// ---- prep: codebook -> fragment-major split-bf16 image (4KB per 16-code chunk) ----
// chunk layout: [B0][B1] = hi feats 0..31/32..63, [B2][B3] = lo; lane(j,g)=g*16+j
// holds code j, features g*8..g*8+7.
__global__ __launch_bounds__(256) void vq_prep(const float* __restrict__ cb,
                                               uint8_t* __restrict__ stage,
                                               float* __restrict__ negcn) {
    int t = blockIdx.x * 256 + threadIdx.x;     // 0..32767, one per 8 floats
    int code = t >> 3, oct = t & 7;
    const float4* cp = (const float4*)(cb + (size_t)code * Dn + oct * 8);
    float4 f0 = cp[0], f1 = cp[1];
    Split8 s = split8(f0, f1);
    int j = code & 15, cc = code >> 4;
    uint8_t* base = stage + (size_t)cc * 4096;
    int dsto = (((oct & 3) * 16 + j) << 4) + ((oct & 4) ? 1024 : 0);
    *(bf16x8*)(base + dsto)        = s.hi;
    *(bf16x8*)(base + 2048 + dsto) = s.lo;
    float n = f0.x*f0.x + f0.y*f0.y + f0.z*f0.z + f0.w*f0.w
            + f1.x*f1.x + f1.y*f1.y + f1.z*f1.z + f1.w*f1.w;
    n += __shfl_xor(n, 1); n += __shfl_xor(n, 2); n += __shfl_xor(n, 4);
    if (oct == 0) negcn[code] = -0.5f * n;
}

__global__ void vq_zero(float* __restrict__ loss_acc, int* __restrict__ flag_cnt) {
    *loss_acc = 0.0f; *flag_cnt = 0;
}

// 1024 blocks x 256 thr; 4 waves: (row-tile = w>>1) x (K-half = w&1); 64 rows/wave.
__global__ __launch_bounds__(256, 3) void vq_main(
    const float* __restrict__ x, const uint8_t* __restrict__ stage,
    const float* __restrict__ negcn, const float* __restrict__ cb,
    float* __restrict__ out, float* __restrict__ loss_acc,
    int* __restrict__ flag_cnt, int* __restrict__ flag_rows) {

    __shared__ float sneg[Kn];                       // -0.5|c|^2
    __shared__ float smv1[4][64], smv2[4][64];
    __shared__ int   smk[4][64];
    __shared__ int   sres[128];

    const int tid = threadIdx.x;
    const int lane = tid & 63, w = tid >> 6;
    const int g = lane >> 4, j = lane & 15;
    const int kh = w & 1;                // K-half
    const int cstart = kh * HCHUNK;
    const int cend = cstart + HCHUNK;

    #pragma unroll
    for (int i = 0; i < 16; ++i) sneg[i*256 + tid] = negcn[i*256 + tid];

    // A fragments: 4 sub-tiles of 16 rows (A layout: row=lane&15, k=(lane>>4)*8+e)
    const int rowbase = blockIdx.x * 128 + (w >> 1) * 64;
    bf16x8 ah[4][2], al[4][2];
    #pragma unroll
    for (int t = 0; t < 4; ++t) {
        const float* xr = x + (size_t)(rowbase + t*16 + j) * Dn + g*8;
        Split8 s0 = split8(*(const float4*)xr,        *(const float4*)(xr + 4));
        Split8 s1 = split8(*(const float4*)(xr + 32), *(const float4*)(xr + 36));
        ah[t][0] = s0.hi; al[t][0] = s0.lo;
        ah[t][1] = s1.hi; al[t][1] = s1.lo;
    }

    // packed top-2: score low byte carries the chunk index (b1 >= b2 invariant)
    float b1[16], b2[16];
    #pragma unroll
    for (int s = 0; s < 16; ++s) { b1[s] = -3.4e38f; b2[s] = -3.4e38f; }

    const uint8_t* sp = stage + (lane << 4);
    // prologue: hi(cstart) into buffer set 0
    bf16x8 h00 = *(const bf16x8*)(sp + ((size_t)cstart << 12));
    bf16x8 h01 = *(const bf16x8*)(sp + ((size_t)cstart << 12) + 1024);
    bf16x8 h10 = {}, h11 = {};
    f32x4 pA0, pA1, pA2, pA3, pB0, pB1, pB2, pB3;
    __syncthreads();     // sneg visible

// Issue chunk C's 24 MFMAs into ACC0..3; rolling loads: lo(C) local, hi(C+1)
// into the HN buffer set. No TOP2 here — deferred one chunk.
#define MFMA_PHASE(ACC0, ACC1, ACC2, ACC3, HB0, HB1, HN0, HN1, C)             \
    {                                                                         \
        const int c_ = (C);                                                   \
        const uint8_t* bp = sp + ((size_t)c_ << 12);                          \
        const int cn_ = (c_ + 1 < cend) ? (c_ + 1) : c_;                      \
        const uint8_t* np = sp + ((size_t)cn_ << 12);                         \
        bf16x8 L0 = *(const bf16x8*)(bp + 2048);                              \
        bf16x8 L1 = *(const bf16x8*)(bp + 3072);                              \
        HN0 = *(const bf16x8*)(np);                                           \
        HN1 = *(const bf16x8*)(np + 1024);                                    \
        float nc = sneg[(c_ << 4) + j];                                       \
        f32x4 ncv = {nc, nc, nc, nc};                                         \
        ACC0 = ncv; ACC1 = ncv; ACC2 = ncv; ACC3 = ncv;                       \
        __builtin_amdgcn_s_setprio(1);                                        \
        ACC0 = __builtin_amdgcn_mfma_f32_16x16x32_bf16(ah[0][0], HB0, ACC0, 0,0,0);\
        ACC1 = __builtin_amdgcn_mfma_f32_16x16x32_bf16(ah[1][0], HB0, ACC1, 0,0,0);\
        ACC2 = __builtin_amdgcn_mfma_f32_16x16x32_bf16(ah[2][0], HB0, ACC2, 0,0,0);\
        ACC3 = __builtin_amdgcn_mfma_f32_16x16x32_bf16(ah[3][0], HB0, ACC3, 0,0,0);\
        ACC0 = __builtin_amdgcn_mfma_f32_16x16x32_bf16(al[0][0], HB0, ACC0, 0,0,0);\
        ACC1 = __builtin_amdgcn_mfma_f32_16x16x32_bf16(al[1][0], HB0, ACC1, 0,0,0);\
        ACC2 = __builtin_amdgcn_mfma_f32_16x16x32_bf16(al[2][0], HB0, ACC2, 0,0,0);\
        ACC3 = __builtin_amdgcn_mfma_f32_16x16x32_bf16(al[3][0], HB0, ACC3, 0,0,0);\
        ACC0 = __builtin_amdgcn_mfma_f32_16x16x32_bf16(ah[0][1], HB1, ACC0, 0,0,0);\
        ACC1 = __builtin_amdgcn_mfma_f32_16x16x32_bf16(ah[1][1], HB1, ACC1, 0,0,0);\
        ACC2 = __builtin_amdgcn_mfma_f32_16x16x32_bf16(ah[2][1], HB1, ACC2, 0,0,0);\
        ACC3 = __builtin_amdgcn_mfma_f32_16x16x32_bf16(ah[3][1], HB1, ACC3, 0,0,0);\
        ACC0 = __builtin_amdgcn_mfma_f32_16x16x32_bf16(al[0][1], HB1, ACC0, 0,0,0);\
        ACC1 = __builtin_amdgcn_mfma_f32_16x16x32_bf16(al[1][1], HB1, ACC1, 0,0,0);\
        ACC2 = __builtin_amdgcn_mfma_f32_16x16x32_bf16(al[2][1], HB1, ACC2, 0,0,0);\
        ACC3 = __builtin_amdgcn_mfma_f32_16x16x32_bf16(al[3][1], HB1, ACC3, 0,0,0);\
        ACC0 = __builtin_amdgcn_mfma_f32_16x16x32_bf16(ah[0][0], L0, ACC0, 0,0,0);\
        ACC1 = __builtin_amdgcn_mfma_f32_16x16x32_bf16(ah[1][0], L0, ACC1, 0,0,0);\
        ACC2 = __builtin_amdgcn_mfma_f32_16x16x32_bf16(ah[2][0], L0, ACC2, 0,0,0);\
        ACC3 = __builtin_amdgcn_mfma_f32_16x16x32_bf16(ah[3][0], L0, ACC3, 0,0,0);\
        ACC0 = __builtin_amdgcn_mfma_f32_16x16x32_bf16(ah[0][1], L1, ACC0, 0,0,0);\
        ACC1 = __builtin_amdgcn_mfma_f32_16x16x32_bf16(ah[1][1], L1, ACC1, 0,0,0);\
        ACC2 = __builtin_amdgcn_mfma_f32_16x16x32_bf16(ah[2][1], L1, ACC2, 0,0,0);\
        ACC3 = __builtin_amdgcn_mfma_f32_16x16x32_bf16(ah[3][1], L1, ACC3, 0,0,0);\
        __builtin_amdgcn_s_setprio(0);                                        \
    }

#define TOP2(ACC, BASE)                                                       \
    _Pragma("unroll")                                                         \
    for (int q = 0; q < 4; ++q) {                                             \
        float vp = __uint_as_float(__builtin_amdgcn_perm(                     \
            __float_as_uint(ACC[q]), cc_, 0x07060500u));                      \
        float ob = b1[(BASE)+q];                                              \
        b2[(BASE)+q] = __builtin_amdgcn_fmed3f(vp, ob, b2[(BASE)+q]);         \
        b1[(BASE)+q] = fmaxf(ob, vp);                                         \
    }

#define TOP2_PHASE(ACC0, ACC1, ACC2, ACC3, C)                                 \
    {                                                                         \
        const uint32_t cc_ = (uint32_t)((C) & 0xFF);                          \
        TOP2(ACC0, 0) TOP2(ACC1, 4) TOP2(ACC2, 8) TOP2(ACC3, 12)              \
    }

    // software pipeline: MFMA(c+1) issued before TOP2(c) retires its acc set.
    MFMA_PHASE(pA0, pA1, pA2, pA3, h00, h01, h10, h11, cstart)
    #pragma unroll 1
    for (int i = 0; i < (HCHUNK - 2) / 2; ++i) {      // 63 iterations
        const int c1 = cstart + 1 + 2 * i;            // odd offset
        MFMA_PHASE(pB0, pB1, pB2, pB3, h10, h11, h00, h01, c1)
        TOP2_PHASE(pA0, pA1, pA2, pA3, c1 - 1)
        MFMA_PHASE(pA0, pA1, pA2, pA3, h00, h01, h10, h11, c1 + 1)
        TOP2_PHASE(pB0, pB1, pB2, pB3, c1)
    }
    MFMA_PHASE(pB0, pB1, pB2, pB3, h10, h11, h00, h01, cend - 1)
    TOP2_PHASE(pA0, pA1, pA2, pA3, cend - 2)
    TOP2_PHASE(pB0, pB1, pB2, pB3, cend - 1)
#undef MFMA_PHASE
#undef TOP2
#undef TOP2_PHASE

    // per-row merge across the 16 code-lanes (D layout: row=(lane>>4)*4+q, col=lane&15)
    #pragma unroll
    for (int s = 0; s < 16; ++s) {
        float v1 = b1[s], v2 = b2[s];
        int kk = (int)((__float_as_uint(v1) & 0xFFu) << 4) + j;   // c*16 + j
        #pragma unroll
        for (int m = 1; m < 16; m <<= 1) {
            float p1 = __shfl_xor(v1, m);
            float p2 = __shfl_xor(v2, m);
            int pk = __shfl_xor(kk, m);
            v2 = fmaxf(fmaxf(v2, p2), fminf(v1, p1));
            bool take = (p1 > v1) || ((p1 == v1) && (pk < kk));
            v1 = take ? p1 : v1;
            kk = take ? pk : kk;
        }
        if (j == 0) {
            int row = (s >> 2)*16 + g*4 + (s & 3);   // 0..63 within wave
            smv1[w][row] = v1; smv2[w][row] = v2; smk[w][row] = kk;
        }
    }
    __syncthreads();

    // cross-K-half merge (disjoint k-ranges; near-ties all fall under TAU -> cleanup)
    if (tid < 128) {
        int rt = tid >> 6, r = tid & 63;
        int wa = rt * 2, wb = wa + 1;
        float v1a = smv1[wa][r], v2a = smv2[wa][r];
        float v1b = smv1[wb][r], v2b = smv2[wb][r];
        int   ka  = smk[wa][r],  kb  = smk[wb][r];
        bool take = v1b > v1a;
        float m1 = take ? v1b : v1a;
        int   kk = take ? kb  : ka;
        float m2 = fmaxf(fmaxf(v2a, v2b), fminf(v1a, v1b));
        int flag = ((m1 - m2) < TAU_S) ? (int)0x80000000 : 0;
        sres[tid] = kk | flag;
    }
    __syncthreads();

    // epilogue: fully coalesced; f enumerates (row, float4) pairs; 128 rows/block
    float ls = 0.f;
    const size_t blockrow = (size_t)blockIdx.x * 128;
    #pragma unroll 1
    for (int it = 0; it < 8; ++it) {
        int f = it * 256 + tid;
        int r = f >> 4, q = f & 15;
        int pk = sres[r];
        int idx = pk & 0x7FFFFFFF;
        bool flagged = pk < 0;
        size_t grow = blockrow + r;
        float4 xx = ((const float4*)(x + grow * Dn))[q];
        float4 qq = ((const float4*)(cb + (size_t)idx * Dn))[q];
        float dx = qq.x - xx.x, dy = qq.y - xx.y, dz = qq.z - xx.z, dw = qq.w - xx.w;
        float4 o; o.x = xx.x + dx; o.y = xx.y + dy; o.z = xx.z + dz; o.w = xx.w + dw;
        ((float4*)(out + grow * Dn))[q] = o;
        if (flagged) {
            if (q == 0) { int p = atomicAdd(flag_cnt, 1); flag_rows[p] = (int)grow; }
        } else {
            ls = fmaf(dx, dx, ls); ls = fmaf(dy, dy, ls);
            ls = fmaf(dz, dz, ls); ls = fmaf(dw, dw, ls);
        }
    }
    #pragma unroll
    for (int m = 1; m < 64; m <<= 1) ls += __shfl_xor(ls, m);
    if (lane == 0) atomicAdd(loss_acc, ls);
}

// fp64 full rescan of flagged rows, 8 rows per block-iteration (codebook read shared).
__global__ __launch_bounds__(256) void vq_cleanup(
    const float* __restrict__ x, const float* __restrict__ cb,
    const int* __restrict__ flag_cnt, const int* __restrict__ flag_rows,
    float* __restrict__ out, float* __restrict__ loss_acc) {
    __shared__ double sxd[8][Dn];
    __shared__ double swb[8][4];
    __shared__ int    swi[8][4];
    const int tid = threadIdx.x;
    const int n = *flag_cnt;

    for (int it = blockIdx.x; it * 8 < n; it += gridDim.x) {
        const int base = it * 8;
        const int nr = min(8, n - base);
        __syncthreads();   // protect sxd/swb from previous iteration readers
        {
            int rr = tid >> 5, e = tid & 31;
            int row = flag_rows[base + ((rr < nr) ? rr : 0)];
            sxd[rr][e]      = (double)x[(size_t)row * Dn + e];
            sxd[rr][e + 32] = (double)x[(size_t)row * Dn + e + 32];
        }
        __syncthreads();

        double best[8]; int bidx[8];
        #pragma unroll
        for (int r2 = 0; r2 < 8; ++r2) { best[r2] = 1.0e300; bidx[r2] = 0x7FFFFFFF; }

        #pragma unroll 1
        for (int i = 0; i < Kn / 256; ++i) {          // 16 codes per thread
            const int k = i * 256 + tid;
            const float* c4 = cb + (size_t)k * Dn;
            double cn = 0.0;
            double d0=0.0,d1=0.0,d2=0.0,d3=0.0,d4=0.0,d5=0.0,d6=0.0,d7=0.0;
            #pragma unroll 8
            for (int e = 0; e < Dn; ++e) {
                double ce = (double)c4[e];
                cn = fma(ce, ce, cn);
                d0 = fma(ce, sxd[0][e], d0);
                d1 = fma(ce, sxd[1][e], d1);
                d2 = fma(ce, sxd[2][e], d2);
                d3 = fma(ce, sxd[3][e], d3);
                d4 = fma(ce, sxd[4][e], d4);
                d5 = fma(ce, sxd[5][e], d5);
                d6 = fma(ce, sxd[6][e], d6);
                d7 = fma(ce, sxd[7][e], d7);
            }
            double dd[8] = { cn - 2.0*d0, cn - 2.0*d1, cn - 2.0*d2, cn - 2.0*d3,
                             cn - 2.0*d4, cn - 2.0*d5, cn - 2.0*d6, cn - 2.0*d7 };
            #pragma unroll
            for (int r2 = 0; r2 < 8; ++r2)
                if (dd[r2] < best[r2] || (dd[r2] == best[r2] && k < bidx[r2])) {
                    best[r2] = dd[r2]; bidx[r2] = k;
                }
        }
        // wave argmin then cross-wave merge (first-occurrence ties)
        #pragma unroll
        for (int r2 = 0; r2 < 8; ++r2) {
            double bb = best[r2]; int bi = bidx[r2];
            #pragma unroll
            for (int m = 1; m < 64; m <<= 1) {
                double pb = __shfl_xor(bb, m);
                int    pi = __shfl_xor(bi, m);
                if (pb < bb || (pb == bb && pi < bi)) { bb = pb; bi = pi; }
            }
            if ((tid & 63) == 0) { swb[r2][tid >> 6] = bb; swi[r2][tid >> 6] = bi; }
        }
        __syncthreads();
        if (tid < 8) {
            double fb = swb[tid][0]; int fi = swi[tid][0];
            #pragma unroll
            for (int wv = 1; wv < 4; ++wv) {
                double pb = swb[tid][wv]; int pi = swi[tid][wv];
                if (pb < fb || (pb == fb && pi < fi)) { fb = pb; fi = pi; }
            }
            swi[tid][0] = fi;
        }
        __syncthreads();

        if (tid < 128) {
            int r2 = tid >> 4, q = tid & 15;
            if (r2 < nr) {
                int row = flag_rows[base + r2];
                int fi  = swi[r2][0];
                float4 xx = ((const float4*)(x + (size_t)row * Dn))[q];
                float4 qq = ((const float4*)(cb + (size_t)fi * Dn))[q];
                float dx = qq.x - xx.x, dy = qq.y - xx.y, dz = qq.z - xx.z, dw = qq.w - xx.w;
                float4 o; o.x = xx.x + dx; o.y = xx.y + dy; o.z = xx.z + dz; o.w = xx.w + dw;
                ((float4*)(out + (size_t)row * Dn))[q] = o;
                float ls = dx*dx + dy*dy + dz*dz + dw*dw;
                ls += __shfl_xor(ls, 1); ls += __shfl_xor(ls, 2);
                ls += __shfl_xor(ls, 4); ls += __shfl_xor(ls, 8);
                if (q == 0) atomicAdd(loss_acc, ls);
            }
        }
    }
}

__global__ void vq_final(float* __restrict__ loss_acc) {
    *loss_acc = *loss_acc * (1.25f / (float)(Bn * Dn));
}

extern "C" void kernel_launch(void* const* d_in, const int* in_sizes, int n_in,
                              void* d_out, int out_size, void* d_ws, size_t ws_size,
                              hipStream_t stream) {
    const float* x  = (const float*)d_in[0];
    const float* cb = (const float*)d_in[1];
    float* out  = (float*)d_out;
    float* loss = out + (size_t)Bn * Dn;

    // ws layout: [negcn 16KB][stage 1MB][flag_cnt 4B][flag_rows 512KB]
    uint8_t* wsb = (uint8_t*)d_ws;
    float*   negcn     = (float*)wsb;
    uint8_t* stage     = wsb + 16384;
    int*     flag_cnt  = (int*)(wsb + 16384 + (size_t)NCHUNK * 4096);
    int*     flag_rows = flag_cnt + 1;

    vq_prep<<<128, 256, 0, stream>>>(cb, stage, negcn);
    vq_zero<<<1, 1, 0, stream>>>(loss, flag_cnt);
    vq_main<<<Bn / 128, 256, 0, stream>>>(x, stage, negcn, cb, out, loss, flag_cnt, flag_rows);
    vq_cleanup<<<512, 256, 0, stream>>>(x, cb, flag_cnt, flag_rows, out, loss);
    vq_final<<<1, 1, 0, stream>>>(loss);
}